// Round 2
// baseline (487.093 us; speedup 1.0000x reference)
//
#include <hip/hip_runtime.h>
#include <hip/hip_bf16.h>
#include <stdint.h>

#define B_   4
#define C_   3
#define N_   128
#define NK   64
#define M_   196
#define MK   98
#define E_   768
#define IW   224
#define IH   224
#define KDIM 768            // C_*16*16
#define ROWS (B_*NK*MK)     // 25088

// d_out (FLOAT32) layout: x | ids_keep | ids_drop | ids_restore
#define O_KEEP 19267584
#define O_DROP 19267840
#define O_REST 19268096

// workspace byte offsets
#define WS_A    0                       // bf16 [25088*768] = 38,535,168 B
#define WS_WB   38535168                // bf16 [768*768]   =  1,179,648 B
#define WS_IDK  39714816                // int  [256]
#define WS_IDP  39715840                // int  [25088]

typedef __attribute__((ext_vector_type(8))) short bf16x8;
typedef __attribute__((ext_vector_type(4))) float f32x4;

__device__ __forceinline__ void gl_lds16(const void* g, void* l) {
  __builtin_amdgcn_global_load_lds(
      (const __attribute__((address_space(1))) unsigned int*)g,
      (__attribute__((address_space(3))) unsigned int*)l, 16, 0, 0);
}

// ---------- outer argsort: B rows of 128, stable rank ----------
__global__ void k_outer(const float* __restrict__ noise, int* __restrict__ idkeep,
                        float* __restrict__ out) {
  int b = blockIdx.x, i = threadIdx.x;
  __shared__ float v[N_];
  v[i] = noise[b * N_ + i];
  __syncthreads();
  float vi = v[i];
  int rank = 0;
  for (int j = 0; j < N_; j++) {
    float vj = v[j];
    rank += (vj < vi) || (vj == vi && j < i);
  }
  if (rank < NK) {
    idkeep[b * NK + rank] = i;
    out[O_KEEP + b * NK + rank] = (float)i;
  } else {
    out[O_DROP + b * NK + (rank - NK)] = (float)i;
  }
  out[O_REST + b * N_ + i] = (float)rank;
}

// ---------- inner argsort: 256 rows of 196, keep first 98 ----------
__global__ void k_inner(const float* __restrict__ noise, int* __restrict__ idp) {
  int bn = blockIdx.x, t = threadIdx.x;
  __shared__ float v[M_];
  if (t < M_) v[t] = noise[bn * M_ + t];
  __syncthreads();
  if (t < M_) {
    float vt = v[t];
    int rank = 0;
    for (int j = 0; j < M_; j++) {
      float vj = v[j];
      rank += (vj < vt) || (vj == vt && j < t);
    }
    if (rank < MK) idp[bn * MK + rank] = t;
  }
}

// ---------- cast proj_w fp32 -> bf16 (layout already e-major, k-contiguous) ----------
__global__ void k_castw(const float* __restrict__ src, __hip_bfloat16* __restrict__ dst) {
  int i = (blockIdx.x * 256 + threadIdx.x) * 8;
  float4 a = *reinterpret_cast<const float4*>(src + i);
  float4 b = *reinterpret_cast<const float4*>(src + i + 4);
  __hip_bfloat16 h[8] = {__float2bfloat16(a.x), __float2bfloat16(a.y),
                         __float2bfloat16(a.z), __float2bfloat16(a.w),
                         __float2bfloat16(b.x), __float2bfloat16(b.y),
                         __float2bfloat16(b.z), __float2bfloat16(b.w)};
  *reinterpret_cast<int4*>(dst + i) = *reinterpret_cast<int4*>(h);
}

// ---------- pack A: gather patches into bf16 [ROWS][768] ----------
// block = (w, bn); stage img row (3 channels x 224) in LDS coalesced,
// then scatter the <=14 matching kept patches' 16 pixels each.
__global__ __launch_bounds__(256) void k_pack(const float* __restrict__ img,
                                              const int* __restrict__ idkeep,
                                              const int* __restrict__ idp,
                                              __hip_bfloat16* __restrict__ A) {
  int w = blockIdx.x;
  int bn = blockIdx.y;
  int t = threadIdx.x;
  __shared__ float rows[C_ * IH];
  __shared__ int mk[14], mmh[14];
  __shared__ int cnt;
  if (t == 0) cnt = 0;
  __syncthreads();
  int b = bn >> 6;
  int sid = idkeep[bn];
  if (t < IH) {
    for (int c = 0; c < C_; c++) {
      rows[c * IH + t] =
          img[(((size_t)(b * C_ + c) * N_ + sid) * IW + w) * IH + t];
    }
  }
  int mw = w % 14, pw = w / 14;
  if (t < MK) {
    int m = idp[bn * MK + t];
    if (m / 14 == mw) {
      int p = atomicAdd(&cnt, 1);
      mk[p] = t;
      mmh[p] = m % 14;
    }
  }
  __syncthreads();
  int tot = cnt * 16;
  if (t < tot) {
    int ki = t >> 4, ph = t & 15;
    int k = mk[ki], mh = mmh[ki];
    size_t rowoff = (size_t)(bn * MK + k) * KDIM;
    for (int c = 0; c < C_; c++) {
      A[rowoff + c * 256 + pw * 16 + ph] =
          __float2bfloat16(rows[c * IH + ph * 14 + mh]);
    }
  }
}

// ---------- GEMM: x[25088 x 768] = A[25088 x 768] * Wb^T[768 x 768] + b + pos ----------
// 128x128 tile, BK=32, 4 waves (2x2), 16x16x32 bf16 MFMA, global_load_lds staging.
#define BK 32
__global__ __launch_bounds__(256) void k_gemm(const __hip_bfloat16* __restrict__ A,
                                              const __hip_bfloat16* __restrict__ Wb,
                                              const float* __restrict__ pb,
                                              const float* __restrict__ pos,
                                              const int* __restrict__ idp,
                                              float* __restrict__ out) {
  __shared__ __align__(16) __hip_bfloat16 As[128 * BK];
  __shared__ __align__(16) __hip_bfloat16 Bs[128 * BK];
  int tid = threadIdx.x;
  int wave = tid >> 6, lane = tid & 63;
  int tm = blockIdx.x, tn = blockIdx.y;
  int wr = wave >> 1, wc = wave & 1;

  f32x4 acc[4][4] = {};

  // staging: each wave's 64 lanes fill 1024B of contiguous LDS (16 rows of 32 bf16)
  int lrow = wave * 16 + (lane >> 2);
  int lchunk = (lane & 3) * 8;
  const __hip_bfloat16* gA0 = A + (size_t)(tm * 128 + lrow) * KDIM + lchunk;
  const __hip_bfloat16* gA1 = gA0 + (size_t)64 * KDIM;
  const __hip_bfloat16* gB0 = Wb + (size_t)(tn * 128 + lrow) * KDIM + lchunk;
  const __hip_bfloat16* gB1 = gB0 + (size_t)64 * KDIM;
  char* ldsA0 = (char*)As + wave * 1024;
  char* ldsA1 = (char*)As + 4096 + wave * 1024;
  char* ldsB0 = (char*)Bs + wave * 1024;
  char* ldsB1 = (char*)Bs + 4096 + wave * 1024;

  int aoff = lane & 15;          // row (A) / col (B) within fragment
  int koff = (lane >> 4) * 8;    // K offset within fragment

  for (int kb = 0; kb < KDIM; kb += BK) {
    gl_lds16(gA0 + kb, ldsA0);
    gl_lds16(gA1 + kb, ldsA1);
    gl_lds16(gB0 + kb, ldsB0);
    gl_lds16(gB1 + kb, ldsB1);
    __syncthreads();
    bf16x8 a[4], bb[4];
#pragma unroll
    for (int mf = 0; mf < 4; mf++)
      a[mf] = *(const bf16x8*)&As[(wr * 64 + mf * 16 + aoff) * BK + koff];
#pragma unroll
    for (int nf = 0; nf < 4; nf++)
      bb[nf] = *(const bf16x8*)&Bs[(wc * 64 + nf * 16 + aoff) * BK + koff];
#pragma unroll
    for (int mf = 0; mf < 4; mf++)
#pragma unroll
      for (int nf = 0; nf < 4; nf++)
        acc[mf][nf] = __builtin_amdgcn_mfma_f32_16x16x32_bf16(a[mf], bb[nf],
                                                              acc[mf][nf], 0, 0, 0);
    __syncthreads();
  }

  // epilogue: + proj_b + inner_pos[m], write fp32
  int col = lane & 15;
  int rgrp = (lane >> 4) * 4;
#pragma unroll
  for (int mf = 0; mf < 4; mf++) {
#pragma unroll
    for (int j = 0; j < 4; j++) {
      int gr = tm * 128 + wr * 64 + mf * 16 + rgrp + j;  // global row = bn*98+k
      int m = idp[gr];
      const float* posrow = pos + (size_t)m * E_;
#pragma unroll
      for (int nf = 0; nf < 4; nf++) {
        int ge = tn * 128 + wc * 64 + nf * 16 + col;
        float vx = acc[mf][nf][j] + pb[ge] + posrow[ge];
        out[(size_t)gr * E_ + ge] = vx;
      }
    }
  }
}

extern "C" void kernel_launch(void* const* d_in, const int* in_sizes, int n_in,
                              void* d_out, int out_size, void* d_ws, size_t ws_size,
                              hipStream_t stream) {
  const float* img = (const float*)d_in[0];
  const float* nout = (const float*)d_in[1];
  const float* ninn = (const float*)d_in[2];
  const float* pw = (const float*)d_in[3];
  const float* pb = (const float*)d_in[4];
  const float* pos = (const float*)d_in[5];
  float* out = (float*)d_out;
  char* ws = (char*)d_ws;
  __hip_bfloat16* A = (__hip_bfloat16*)(ws + WS_A);
  __hip_bfloat16* Wb = (__hip_bfloat16*)(ws + WS_WB);
  int* idkeep = (int*)(ws + WS_IDK);
  int* idp = (int*)(ws + WS_IDP);

  hipLaunchKernelGGL(k_outer, dim3(B_), dim3(N_), 0, stream, nout, idkeep, out);
  hipLaunchKernelGGL(k_inner, dim3(B_ * NK), dim3(256), 0, stream, ninn, idp);
  hipLaunchKernelGGL(k_castw, dim3((E_ * KDIM) / (256 * 8)), dim3(256), 0, stream, pw, Wb);
  hipLaunchKernelGGL(k_pack, dim3(IW, B_ * NK), dim3(256), 0, stream, img, idkeep, idp, A);
  hipLaunchKernelGGL(k_gemm, dim3(ROWS / 128, E_ / 128), dim3(256), 0, stream,
                     A, Wb, pb, pos, idp, out);
}